// Round 1
// baseline (459.980 us; speedup 1.0000x reference)
//
#include <hip/hip_runtime.h>
#include <math.h>

// ---------------------------------------------------------------------------
// EdgeAttnConv: out[d] = x[d] + (Σ_{e: dst=d} w_e·(z[src_e] + ea_e@We)) / (Σ w_e + 1e-8)
//   w_e = exp(score_e - max_d),  score_e = leaky_relu(zs[src]+zd[dst]+ea_e·(We@att_edge), 0.2)
//   z = x@Wn, zs = z@att_src, zd = z@att_dst
// Identity used: Σ w·(ea@We) = (Σ w·ea)@We  -> never materialize e=[E,64].
// Aggregation: CSR-by-dst built on the fly (count/scan/scatter), wave-per-node.
// ---------------------------------------------------------------------------

__device__ __forceinline__ float wave_max64(float v) {
#pragma unroll
  for (int o = 32; o > 0; o >>= 1) v = fmaxf(v, __shfl_xor(v, o));
  return v;
}
__device__ __forceinline__ float wave_sum64(float v) {
#pragma unroll
  for (int o = 32; o > 0; o >>= 1) v += __shfl_xor(v, o);
  return v;
}

// --- tiny prep: weA = We @ att_edge  (16), zero global edge counter --------
__global__ __launch_bounds__(64) void k_prep(const float* __restrict__ We,
                                             const float* __restrict__ att_edge,
                                             float* __restrict__ weA,
                                             int* __restrict__ total) {
  int t = threadIdx.x;
  if (t < 16) {
    float a = 0.f;
#pragma unroll
    for (int c = 0; c < 64; ++c) a = fmaf(We[t * 64 + c], att_edge[c], a);
    weA[t] = a;
  }
  if (t == 16) *total = 0;
}

// --- node kernel: wave per row. z=x@Wn, zs=z·att_src, zd=z·att_dst, count=0 -
__global__ __launch_bounds__(256) void k_node(
    const float* __restrict__ x, const float* __restrict__ Wn,
    const float* __restrict__ att_src, const float* __restrict__ att_dst,
    float* __restrict__ z, float* __restrict__ zs, float* __restrict__ zd,
    int* __restrict__ count, int n) {
  const int lane = threadIdx.x & 63;
  const int wid = (blockIdx.x * blockDim.x + threadIdx.x) >> 6;
  const int nw = (gridDim.x * blockDim.x) >> 6;
  float wn[64];  // my output column of Wn
#pragma unroll
  for (int k = 0; k < 64; ++k) wn[k] = Wn[k * 64 + lane];
  const float as = att_src[lane], ad = att_dst[lane];
  for (int r = wid; r < n; r += nw) {
    float xv = x[(size_t)r * 64 + lane];
    float a0 = 0.f, a1 = 0.f, a2 = 0.f, a3 = 0.f;  // break dep chain
#pragma unroll
    for (int k = 0; k < 64; k += 4) {
      a0 = fmaf(__shfl(xv, k), wn[k], a0);
      a1 = fmaf(__shfl(xv, k + 1), wn[k + 1], a1);
      a2 = fmaf(__shfl(xv, k + 2), wn[k + 2], a2);
      a3 = fmaf(__shfl(xv, k + 3), wn[k + 3], a3);
    }
    float acc = (a0 + a1) + (a2 + a3);
    z[(size_t)r * 64 + lane] = acc;
    float ps = wave_sum64(acc * as);
    float pd = wave_sum64(acc * ad);
    if (lane == 0) {
      zs[r] = ps;
      zd[r] = pd;
      count[r] = 0;
    }
  }
}

// --- count edges per dst ----------------------------------------------------
__global__ __launch_bounds__(256) void k_count(const int* __restrict__ dst,
                                               int* __restrict__ count, int e) {
  int i = blockIdx.x * 256 + threadIdx.x;
  if (i < e) atomicAdd(&count[dst[i]], 1);
}

// --- offsets: block scan of counts + one atomic per block (order-free) ------
__global__ __launch_bounds__(256) void k_offsets(const int* __restrict__ count,
                                                 int* __restrict__ start,
                                                 int* __restrict__ cursor,
                                                 int* __restrict__ total, int n) {
  __shared__ int sdata[256];
  __shared__ int sbase;
  const int tid = threadIdx.x;
  const int i = blockIdx.x * 256 + tid;
  int c = (i < n) ? count[i] : 0;
  int v = c;
  sdata[tid] = v;
  __syncthreads();
  for (int off = 1; off < 256; off <<= 1) {
    int t = (tid >= off) ? sdata[tid - off] : 0;
    __syncthreads();
    v += t;
    sdata[tid] = v;
    __syncthreads();
  }
  if (tid == 255) sbase = atomicAdd(total, v);
  __syncthreads();
  int excl = v - c;
  if (i < n) {
    start[i] = sbase + excl;
    cursor[i] = sbase + excl;
  }
}

// --- scatter edges into dst-grouped records {edge_id, src} ------------------
__global__ __launch_bounds__(256) void k_scatter(const int* __restrict__ src,
                                                 const int* __restrict__ dst,
                                                 int* __restrict__ cursor,
                                                 uint2* __restrict__ es, int e) {
  int i = blockIdx.x * 256 + threadIdx.x;
  if (i < e) {
    int d = dst[i];
    int pos = atomicAdd(&cursor[d], 1);
    es[pos] = make_uint2((unsigned)i, (unsigned)src[i]);
  }
}

// --- aggregate: one wave per dst node, online softmax, no atomics -----------
__global__ __launch_bounds__(256) void k_agg(
    const float* __restrict__ x, const float* __restrict__ z,
    const float* __restrict__ zs, const float* __restrict__ zd,
    const float* __restrict__ ea, const float* __restrict__ We,
    const float* __restrict__ weA, const int* __restrict__ start,
    const int* __restrict__ endp, const uint2* __restrict__ es,
    float* __restrict__ out, int n) {
  const int lane = threadIdx.x & 63;
  const int d = blockIdx.x * 4 + (threadIdx.x >> 6);
  if (d >= n) return;
  float we16[16];  // my output column of We
#pragma unroll
  for (int k = 0; k < 16; ++k) we16[k] = We[k * 64 + lane];
  float wA[16];
#pragma unroll
  for (int k = 0; k < 16; ++k) wA[k] = weA[k];

  const int s0 = start[d], s1 = endp[d];
  const float zdv = zd[d];
  float m = -INFINITY, dsum = 0.f, msg = 0.f, ag = 0.f;

  for (int c0 = s0; c0 < s1; c0 += 64) {
    const int nc = min(64, s1 - c0);
    const bool act = lane < nc;
    uint2 e2 = make_uint2(0u, 0u);
    float sc = -INFINITY;
    if (act) {
      e2 = es[c0 + lane];
      float zsv = zs[e2.y];
      const float4* eap = (const float4*)(ea + (size_t)e2.x * 16);
      float4 q0 = eap[0], q1 = eap[1], q2 = eap[2], q3 = eap[3];
      float sed = q0.x * wA[0] + q0.y * wA[1] + q0.z * wA[2] + q0.w * wA[3] +
                  q1.x * wA[4] + q1.y * wA[5] + q1.z * wA[6] + q1.w * wA[7] +
                  q2.x * wA[8] + q2.y * wA[9] + q2.z * wA[10] + q2.w * wA[11] +
                  q3.x * wA[12] + q3.y * wA[13] + q3.z * wA[14] + q3.w * wA[15];
      float s = zsv + zdv + sed;
      sc = (s > 0.f) ? s : 0.2f * s;
    }
    // online-softmax chunk combine
    float mc = wave_max64(sc);
    float mnew = fmaxf(m, mc);
    float rs = __expf(m - mnew);  // m=-inf first chunk -> rs=0, harmless
    float w = act ? __expf(sc - mnew) : 0.f;
    m = mnew;
    dsum = dsum * rs + w;  // per-lane partial over my own edges
    msg *= rs;
    ag *= rs;
    // uniform loop: accumulate w·z[src] (lane=col) and w·ea (lanes 0..15)
    int sjv = (int)e2.y, ejv = (int)e2.x;
    for (int jj = 0; jj < nc; ++jj) {
      float wj = __shfl(w, jj);
      int sj = __shfl(sjv, jj);
      int ej = __shfl(ejv, jj);
      msg = fmaf(wj, z[(size_t)sj * 64 + lane], msg);
      float eav = ea[(size_t)ej * 16 + (lane & 15)];
      ag = fmaf(wj, eav, ag);
    }
  }

  float dtot = wave_sum64(dsum);
  float evec = 0.f;
#pragma unroll
  for (int k = 0; k < 16; ++k) evec = fmaf(__shfl(ag, k), we16[k], evec);
  float res = (msg + evec) / (dtot + 1e-8f) + x[(size_t)d * 64 + lane];
  out[(size_t)d * 64 + lane] = res;
}

extern "C" void kernel_launch(void* const* d_in, const int* in_sizes, int n_in,
                              void* d_out, int out_size, void* d_ws, size_t ws_size,
                              hipStream_t stream) {
  const float* x = (const float*)d_in[0];
  const int* ei = (const int*)d_in[1];
  const float* ea = (const float*)d_in[2];
  const float* Wn = (const float*)d_in[3];
  const float* We = (const float*)d_in[4];
  const float* att_src = (const float*)d_in[5];
  const float* att_dst = (const float*)d_in[6];
  const float* att_edge = (const float*)d_in[7];
  float* out = (float*)d_out;

  const int N = in_sizes[0] / 64;
  const int E = in_sizes[1] / 2;
  const int* src = ei;
  const int* dst = ei + E;

  // workspace carve (256B aligned)
  char* p = (char*)d_ws;
  auto carve = [&](size_t bytes) {
    void* q = (void*)p;
    p += (bytes + 255) & ~(size_t)255;
    return q;
  };
  float* z = (float*)carve((size_t)N * 64 * sizeof(float));
  float* zs = (float*)carve((size_t)N * sizeof(float));
  float* zd = (float*)carve((size_t)N * sizeof(float));
  int* count = (int*)carve((size_t)N * sizeof(int));
  int* startp = (int*)carve((size_t)N * sizeof(int));
  int* cursor = (int*)carve((size_t)N * sizeof(int));
  float* weA = (float*)carve(64);
  int* total = (int*)carve(64);
  uint2* es = (uint2*)carve((size_t)E * sizeof(uint2));

  k_prep<<<1, 64, 0, stream>>>(We, att_edge, weA, total);
  k_node<<<1024, 256, 0, stream>>>(x, Wn, att_src, att_dst, z, zs, zd, count, N);
  k_count<<<(E + 255) / 256, 256, 0, stream>>>(dst, count, E);
  k_offsets<<<(N + 255) / 256, 256, 0, stream>>>(count, startp, cursor, total, N);
  k_scatter<<<(E + 255) / 256, 256, 0, stream>>>(src, dst, cursor, es, E);
  // after scatter, cursor[d] == end offset of d's region
  k_agg<<<(N + 3) / 4, 256, 0, stream>>>(x, z, zs, zd, ea, We, weA, startp,
                                         cursor, es, out, N);
}

// Round 2
// 339.075 us; speedup vs baseline: 1.3566x; 1.3566x over previous
//
#include <hip/hip_runtime.h>
#include <math.h>

// ---------------------------------------------------------------------------
// EdgeAttnConv: out[d] = x[d] + (Σ_{e: dst=d} w_e·(z[src_e] + ea_e@We)) / (Σ w_e + 1e-8)
//   w_e = exp(score_e - max_d),  score_e = leaky_relu(zs[src]+zd[dst]+ea_e·weA, 0.2)
//   z = x@Wn, zs = z@att_src, zd = z@att_dst, weA = We@att_edge
// Identity: Σ w·(ea@We) = (Σ w·ea)@We  -> e=[E,64] never materialized.
// Pipeline: prep -> node (z,zs,zd) -> count -> offsets -> scatter(+score) ->
//           agg (wave per node, 4 edges/step, online softmax, no atomics).
// ---------------------------------------------------------------------------

__device__ __forceinline__ float wave_max64(float v) {
#pragma unroll
  for (int o = 32; o > 0; o >>= 1) v = fmaxf(v, __shfl_xor(v, o));
  return v;
}
__device__ __forceinline__ float wave_sum64(float v) {
#pragma unroll
  for (int o = 32; o > 0; o >>= 1) v += __shfl_xor(v, o);
  return v;
}

// --- tiny prep: weA = We @ att_edge  (16), zero global edge counter --------
__global__ __launch_bounds__(64) void k_prep(const float* __restrict__ We,
                                             const float* __restrict__ att_edge,
                                             float* __restrict__ weA,
                                             int* __restrict__ total) {
  int t = threadIdx.x;
  if (t < 16) {
    float a = 0.f;
#pragma unroll
    for (int c = 0; c < 64; ++c) a = fmaf(We[t * 64 + c], att_edge[c], a);
    weA[t] = a;
  }
  if (t == 16) *total = 0;
}

// --- node kernel: wave per row. z=x@Wn, zs=z·att_src, zd=z·att_dst, count=0 -
__global__ __launch_bounds__(256) void k_node(
    const float* __restrict__ x, const float* __restrict__ Wn,
    const float* __restrict__ att_src, const float* __restrict__ att_dst,
    float* __restrict__ z, float* __restrict__ zs, float* __restrict__ zd,
    int* __restrict__ count, int n) {
  const int lane = threadIdx.x & 63;
  const int wid = (blockIdx.x * blockDim.x + threadIdx.x) >> 6;
  const int nw = (gridDim.x * blockDim.x) >> 6;
  float wn[64];  // my output column of Wn
#pragma unroll
  for (int k = 0; k < 64; ++k) wn[k] = Wn[k * 64 + lane];
  const float as = att_src[lane], ad = att_dst[lane];
  for (int r = wid; r < n; r += nw) {
    float xv = x[(size_t)r * 64 + lane];
    float a0 = 0.f, a1 = 0.f, a2 = 0.f, a3 = 0.f;  // break dep chain
#pragma unroll
    for (int k = 0; k < 64; k += 4) {
      a0 = fmaf(__shfl(xv, k), wn[k], a0);
      a1 = fmaf(__shfl(xv, k + 1), wn[k + 1], a1);
      a2 = fmaf(__shfl(xv, k + 2), wn[k + 2], a2);
      a3 = fmaf(__shfl(xv, k + 3), wn[k + 3], a3);
    }
    float acc = (a0 + a1) + (a2 + a3);
    z[(size_t)r * 64 + lane] = acc;
    float ps = wave_sum64(acc * as);
    float pd = wave_sum64(acc * ad);
    if (lane == 0) {
      zs[r] = ps;
      zd[r] = pd;
      count[r] = 0;
    }
  }
}

// --- count edges per dst ----------------------------------------------------
__global__ __launch_bounds__(256) void k_count(const int* __restrict__ dst,
                                               int* __restrict__ count, int e) {
  int i = blockIdx.x * 256 + threadIdx.x;
  if (i < e) atomicAdd(&count[dst[i]], 1);
}

// --- offsets: block scan of counts + one atomic per block (order-free) ------
__global__ __launch_bounds__(256) void k_offsets(const int* __restrict__ count,
                                                 int* __restrict__ start,
                                                 int* __restrict__ cursor,
                                                 int* __restrict__ total, int n) {
  __shared__ int sdata[256];
  __shared__ int sbase;
  const int tid = threadIdx.x;
  const int i = blockIdx.x * 256 + tid;
  int c = (i < n) ? count[i] : 0;
  int v = c;
  sdata[tid] = v;
  __syncthreads();
  for (int off = 1; off < 256; off <<= 1) {
    int t = (tid >= off) ? sdata[tid - off] : 0;
    __syncthreads();
    v += t;
    sdata[tid] = v;
    __syncthreads();
  }
  if (tid == 255) sbase = atomicAdd(total, v);
  __syncthreads();
  int excl = v - c;
  if (i < n) {
    start[i] = sbase + excl;
    cursor[i] = sbase + excl;
  }
}

// --- scatter edges into dst-grouped records {edge, src, score} --------------
// Score computed HERE, edge-parallel, with ea streamed coalesced.
__global__ __launch_bounds__(256) void k_scatter(
    const int* __restrict__ src, const int* __restrict__ dst,
    const float* __restrict__ zs, const float* __restrict__ zd,
    const float* __restrict__ ea, const float* __restrict__ weA,
    int* __restrict__ cursor, uint4* __restrict__ es, int e) {
  int i = blockIdx.x * 256 + threadIdx.x;
  if (i >= e) return;
  int s = src[i], d = dst[i];
  const float4* eap = (const float4*)(ea + (size_t)i * 16);
  float4 q0 = eap[0], q1 = eap[1], q2 = eap[2], q3 = eap[3];
  float sed = q0.x * weA[0] + q0.y * weA[1] + q0.z * weA[2] + q0.w * weA[3] +
              q1.x * weA[4] + q1.y * weA[5] + q1.z * weA[6] + q1.w * weA[7] +
              q2.x * weA[8] + q2.y * weA[9] + q2.z * weA[10] + q2.w * weA[11] +
              q3.x * weA[12] + q3.y * weA[13] + q3.z * weA[14] + q3.w * weA[15];
  float sv = zs[s] + zd[d] + sed;
  float sc = (sv > 0.f) ? sv : 0.2f * sv;
  int pos = atomicAdd(&cursor[d], 1);
  es[pos] = make_uint4((unsigned)i, (unsigned)s, __float_as_uint(sc), 0u);
}

// --- aggregate: one wave per dst node, 4 edges per step, online softmax -----
__global__ __launch_bounds__(256) void k_agg(
    const float* __restrict__ x, const float* __restrict__ z,
    const float* __restrict__ ea, const float* __restrict__ We,
    const int* __restrict__ start, const int* __restrict__ endp,
    const uint4* __restrict__ es, float* __restrict__ out, int n) {
  const int lane = threadIdx.x & 63;
  const int grp = lane >> 4;   // 4 groups of 16 lanes; group handles edge jj%4==grp
  const int gl = lane & 15;    // lane-in-group: owns cols 4*gl..4*gl+3 (float4)
  const int d = blockIdx.x * 4 + (threadIdx.x >> 6);
  if (d >= n) return;

  const int s0 = start[d], s1 = endp[d];
  float m = -INFINITY, dsum = 0.f, ag = 0.f;
  float4 msg = make_float4(0.f, 0.f, 0.f, 0.f);

  for (int c0 = s0; c0 < s1; c0 += 64) {
    const int nc = min(64, s1 - c0);
    const bool act = lane < nc;
    uint4 rec = act ? es[c0 + lane] : make_uint4(0u, 0u, 0u, 0u);
    float sc = act ? __uint_as_float(rec.z) : -INFINITY;
    // online-softmax chunk combine
    float mc = wave_max64(sc);
    float mnew = fmaxf(m, mc);
    float rs = __expf(m - mnew);  // first chunk: exp(-inf - finite) = 0
    float w = act ? __expf(sc - mnew) : 0.f;
    m = mnew;
    dsum = dsum * rs + w;
    msg.x *= rs; msg.y *= rs; msg.z *= rs; msg.w *= rs;
    ag *= rs;
    int sv = act ? (int)rec.y : 0;  // inactive: row 0, weight 0
    int ev = act ? (int)rec.x : 0;
    // gather: group grp handles edges jj = 4t+grp; unroll x2 for ILP
    const int steps = (nc + 3) >> 2;
    int t = 0;
    for (; t + 2 <= steps; t += 2) {
      int jj0 = (t << 2) + grp, jj1 = jj0 + 4;
      float w0 = __shfl(w, jj0), w1 = __shfl(w, jj1);
      int s0v = __shfl(sv, jj0), s1v = __shfl(sv, jj1);
      int e0v = __shfl(ev, jj0), e1v = __shfl(ev, jj1);
      const float4 z0 = *(const float4*)(z + (size_t)s0v * 64 + gl * 4);
      const float4 z1 = *(const float4*)(z + (size_t)s1v * 64 + gl * 4);
      float a0 = ea[(size_t)e0v * 16 + gl];
      float a1 = ea[(size_t)e1v * 16 + gl];
      msg.x = fmaf(w0, z0.x, fmaf(w1, z1.x, msg.x));
      msg.y = fmaf(w0, z0.y, fmaf(w1, z1.y, msg.y));
      msg.z = fmaf(w0, z0.z, fmaf(w1, z1.z, msg.z));
      msg.w = fmaf(w0, z0.w, fmaf(w1, z1.w, msg.w));
      ag = fmaf(w0, a0, fmaf(w1, a1, ag));
    }
    if (t < steps) {
      int jj0 = (t << 2) + grp;
      float w0 = __shfl(w, jj0);
      int s0v = __shfl(sv, jj0);
      int e0v = __shfl(ev, jj0);
      const float4 z0 = *(const float4*)(z + (size_t)s0v * 64 + gl * 4);
      float a0 = ea[(size_t)e0v * 16 + gl];
      msg.x = fmaf(w0, z0.x, msg.x);
      msg.y = fmaf(w0, z0.y, msg.y);
      msg.z = fmaf(w0, z0.z, msg.z);
      msg.w = fmaf(w0, z0.w, msg.w);
      ag = fmaf(w0, a0, ag);
    }
  }

  float dtot = wave_sum64(dsum);
  // combine the 4 groups' partials (lanes with equal gl share a column range)
  msg.x += __shfl_xor(msg.x, 16); msg.x += __shfl_xor(msg.x, 32);
  msg.y += __shfl_xor(msg.y, 16); msg.y += __shfl_xor(msg.y, 32);
  msg.z += __shfl_xor(msg.z, 16); msg.z += __shfl_xor(msg.z, 32);
  msg.w += __shfl_xor(msg.w, 16); msg.w += __shfl_xor(msg.w, 32);
  ag += __shfl_xor(ag, 16); ag += __shfl_xor(ag, 32);

  // evec = (Σ w·ea) @ We, per-lane float4 of columns 4gl..4gl+3
  const float4* We4 = (const float4*)We;
  float4 evec = make_float4(0.f, 0.f, 0.f, 0.f);
#pragma unroll
  for (int k = 0; k < 16; ++k) {
    float agk = __shfl(ag, k);  // lane k holds element k after xor-combine
    float4 wef = We4[k * 16 + gl];
    evec.x = fmaf(agk, wef.x, evec.x);
    evec.y = fmaf(agk, wef.y, evec.y);
    evec.z = fmaf(agk, wef.z, evec.z);
    evec.w = fmaf(agk, wef.w, evec.w);
  }

  if (grp == 0) {
    float inv = 1.f / (dtot + 1e-8f);
    const float4 xr = *(const float4*)(x + (size_t)d * 64 + gl * 4);
    float4 r;
    r.x = fmaf(msg.x + evec.x, inv, xr.x);
    r.y = fmaf(msg.y + evec.y, inv, xr.y);
    r.z = fmaf(msg.z + evec.z, inv, xr.z);
    r.w = fmaf(msg.w + evec.w, inv, xr.w);
    *(float4*)(out + (size_t)d * 64 + gl * 4) = r;
  }
}

extern "C" void kernel_launch(void* const* d_in, const int* in_sizes, int n_in,
                              void* d_out, int out_size, void* d_ws, size_t ws_size,
                              hipStream_t stream) {
  const float* x = (const float*)d_in[0];
  const int* ei = (const int*)d_in[1];
  const float* ea = (const float*)d_in[2];
  const float* Wn = (const float*)d_in[3];
  const float* We = (const float*)d_in[4];
  const float* att_src = (const float*)d_in[5];
  const float* att_dst = (const float*)d_in[6];
  const float* att_edge = (const float*)d_in[7];
  float* out = (float*)d_out;

  const int N = in_sizes[0] / 64;
  const int E = in_sizes[1] / 2;
  const int* src = ei;
  const int* dst = ei + E;

  // workspace carve (256B aligned)
  char* p = (char*)d_ws;
  auto carve = [&](size_t bytes) {
    void* q = (void*)p;
    p += (bytes + 255) & ~(size_t)255;
    return q;
  };
  float* z = (float*)carve((size_t)N * 64 * sizeof(float));
  float* zs = (float*)carve((size_t)N * sizeof(float));
  float* zd = (float*)carve((size_t)N * sizeof(float));
  int* count = (int*)carve((size_t)N * sizeof(int));
  int* startp = (int*)carve((size_t)N * sizeof(int));
  int* cursor = (int*)carve((size_t)N * sizeof(int));
  float* weA = (float*)carve(64);
  int* total = (int*)carve(64);
  uint4* es = (uint4*)carve((size_t)E * sizeof(uint4));

  k_prep<<<1, 64, 0, stream>>>(We, att_edge, weA, total);
  k_node<<<2048, 256, 0, stream>>>(x, Wn, att_src, att_dst, z, zs, zd, count, N);
  k_count<<<(E + 255) / 256, 256, 0, stream>>>(dst, count, E);
  k_offsets<<<(N + 255) / 256, 256, 0, stream>>>(count, startp, cursor, total, N);
  k_scatter<<<(E + 255) / 256, 256, 0, stream>>>(src, dst, zs, zd, ea, weA,
                                                 cursor, es, E);
  // after scatter, cursor[d] == end offset of d's region
  k_agg<<<(N + 3) / 4, 256, 0, stream>>>(x, z, ea, We, startp, cursor, es, out, N);
}

// Round 3
// 317.161 us; speedup vs baseline: 1.4503x; 1.0691x over previous
//
#include <hip/hip_runtime.h>
#include <math.h>

// ---------------------------------------------------------------------------
// EdgeAttnConv: out[d] = x[d] + (Σ_{e: dst=d} w_e·(z[src_e] + ea_e@We)) / (Σ w_e + 1e-8)
//   w_e = exp(score_e - max_d),  score_e = leaky_relu(zs[src]+zd[dst]+ea_e·weA, 0.2)
//   z = x@Wn, zs = z@att_src, zd = z@att_dst, weA = We@att_edge
// Identity: Σ w·(ea@We) = (Σ w·ea)@We  -> e=[E,64] never materialized.
// Pipeline: memset(count) -> prep -> countpos (atomics only, light pass) ->
//           node -> offsets -> scatter (atomic-FREE heavy pass, streams ea) ->
//           agg (wave per node, grid-stride + next-node prefetch).
// ---------------------------------------------------------------------------

__device__ __forceinline__ float wave_max64(float v) {
#pragma unroll
  for (int o = 32; o > 0; o >>= 1) v = fmaxf(v, __shfl_xor(v, o));
  return v;
}
__device__ __forceinline__ float wave_sum64(float v) {
#pragma unroll
  for (int o = 32; o > 0; o >>= 1) v += __shfl_xor(v, o);
  return v;
}

// --- tiny prep: weA = We @ att_edge (16), zero global scan base -------------
__global__ __launch_bounds__(64) void k_prep(const float* __restrict__ We,
                                             const float* __restrict__ att_edge,
                                             float* __restrict__ weA,
                                             int* __restrict__ total) {
  int t = threadIdx.x;
  if (t < 16) {
    float a = 0.f;
#pragma unroll
    for (int c = 0; c < 64; ++c) a = fmaf(We[t * 64 + c], att_edge[c], a);
    weA[t] = a;
  }
  if (t == 16) *total = 0;
}

// --- count + per-edge position within its dst bucket (the ONLY atomic pass) -
__global__ __launch_bounds__(256) void k_countpos(const int* __restrict__ dst,
                                                  int* __restrict__ count,
                                                  int* __restrict__ pos, int e) {
  int i = blockIdx.x * 256 + threadIdx.x;
  if (i < e) pos[i] = atomicAdd(&count[dst[i]], 1);
}

// --- node kernel: wave per row. z=x@Wn, zs=z·att_src, zd=z·att_dst ----------
__global__ __launch_bounds__(256) void k_node(
    const float* __restrict__ x, const float* __restrict__ Wn,
    const float* __restrict__ att_src, const float* __restrict__ att_dst,
    float* __restrict__ z, float* __restrict__ zs, float* __restrict__ zd,
    int n) {
  const int lane = threadIdx.x & 63;
  const int wid = (blockIdx.x * blockDim.x + threadIdx.x) >> 6;
  const int nw = (gridDim.x * blockDim.x) >> 6;
  float wn[64];  // my output column of Wn
#pragma unroll
  for (int k = 0; k < 64; ++k) wn[k] = Wn[k * 64 + lane];
  const float as = att_src[lane], ad = att_dst[lane];
  for (int r = wid; r < n; r += nw) {
    float xv = x[(size_t)r * 64 + lane];
    float a0 = 0.f, a1 = 0.f, a2 = 0.f, a3 = 0.f;
#pragma unroll
    for (int k = 0; k < 64; k += 4) {
      a0 = fmaf(__shfl(xv, k), wn[k], a0);
      a1 = fmaf(__shfl(xv, k + 1), wn[k + 1], a1);
      a2 = fmaf(__shfl(xv, k + 2), wn[k + 2], a2);
      a3 = fmaf(__shfl(xv, k + 3), wn[k + 3], a3);
    }
    float acc = (a0 + a1) + (a2 + a3);
    z[(size_t)r * 64 + lane] = acc;
    float ps = wave_sum64(acc * as);
    float pd = wave_sum64(acc * ad);
    if (lane == 0) {
      zs[r] = ps;
      zd[r] = pd;
    }
  }
}

// --- offsets: block scan of counts + one atomic per block (order-free) ------
__global__ __launch_bounds__(256) void k_offsets(const int* __restrict__ count,
                                                 int* __restrict__ start,
                                                 int* __restrict__ total, int n) {
  __shared__ int sdata[256];
  __shared__ int sbase;
  const int tid = threadIdx.x;
  const int i = blockIdx.x * 256 + tid;
  int c = (i < n) ? count[i] : 0;
  int v = c;
  sdata[tid] = v;
  __syncthreads();
  for (int off = 1; off < 256; off <<= 1) {
    int t = (tid >= off) ? sdata[tid - off] : 0;
    __syncthreads();
    v += t;
    sdata[tid] = v;
    __syncthreads();
  }
  if (tid == 255) sbase = atomicAdd(total, v);
  __syncthreads();
  if (i < n) start[i] = sbase + (v - c);
}

// --- scatter: atomic-free heavy pass. score computed here, ea streamed ------
__global__ __launch_bounds__(256) void k_scatter(
    const int* __restrict__ src, const int* __restrict__ dst,
    const int* __restrict__ pos, const float* __restrict__ zs,
    const float* __restrict__ zd, const float* __restrict__ ea,
    const float* __restrict__ weA, const int* __restrict__ start,
    uint4* __restrict__ es, int e) {
  int i = blockIdx.x * 256 + threadIdx.x;
  if (i >= e) return;
  int s = src[i], d = dst[i], p = pos[i];
  int slot = start[d] + p;  // start[] gather is L2-resident (400 KB)
  const float4* eap = (const float4*)(ea + (size_t)i * 16);
  float4 q0 = eap[0], q1 = eap[1], q2 = eap[2], q3 = eap[3];
  float sed = q0.x * weA[0] + q0.y * weA[1] + q0.z * weA[2] + q0.w * weA[3] +
              q1.x * weA[4] + q1.y * weA[5] + q1.z * weA[6] + q1.w * weA[7] +
              q2.x * weA[8] + q2.y * weA[9] + q2.z * weA[10] + q2.w * weA[11] +
              q3.x * weA[12] + q3.y * weA[13] + q3.z * weA[14] + q3.w * weA[15];
  float sv = zs[s] + zd[d] + sed;
  float sc = (sv > 0.f) ? sv : 0.2f * sv;
  es[slot] = make_uint4((unsigned)i, (unsigned)s, __float_as_uint(sc), 0u);
}

// --- aggregate: wave per node, grid-stride, next-node prefetch --------------
__global__ __launch_bounds__(256) void k_agg(
    const float* __restrict__ x, const float* __restrict__ z,
    const float* __restrict__ ea, const float* __restrict__ We,
    const int* __restrict__ start, const int* __restrict__ count,
    const uint4* __restrict__ es, float* __restrict__ out, int n) {
  const int lane = threadIdx.x & 63;
  const int grp = lane >> 4;   // 4 groups of 16; group handles edges jj%4==grp
  const int gl = lane & 15;    // owns columns 4*gl..4*gl+3
  const int nw = (gridDim.x * blockDim.x) >> 6;
  int d = (blockIdx.x * blockDim.x + threadIdx.x) >> 6;
  if (d >= n) return;

  const uint4 REC0 = make_uint4(0u, 0u, __float_as_uint(-1e30f), 0u);

  int s0 = start[d], cnt = count[d];
  uint4 rec = REC0;
  if (lane < cnt) rec = es[s0 + lane];  // first chunk prefetch

  while (d < n) {
    // prefetch next node while computing this one
    int dn = d + nw;
    int sn0 = 0, cn = 0;
    uint4 recn = REC0;
    if (dn < n) {
      sn0 = start[dn];
      cn = count[dn];
      if (lane < cn) recn = es[sn0 + lane];
    }

    float m = -1e30f, dsum = 0.f, ag = 0.f;
    float4 msg = make_float4(0.f, 0.f, 0.f, 0.f);

    for (int c0 = 0; c0 < cnt; c0 += 64) {
      const int nc = min(64, cnt - c0);
      const bool act = lane < nc;
      uint4 cur = rec;
      if (c0 > 0) cur = act ? es[s0 + c0 + lane] : REC0;  // rare (deg > 64)
      float sc = __uint_as_float(cur.z);
      // online-softmax chunk combine (sentinel -1e30 keeps exp finite)
      float mc = wave_max64(sc);
      float mnew = fmaxf(m, mc);
      float rs = __expf(m - mnew);
      float w = act ? __expf(sc - mnew) : 0.f;
      m = mnew;
      dsum = dsum * rs + w;
      msg.x *= rs; msg.y *= rs; msg.z *= rs; msg.w *= rs;
      ag *= rs;
      int sv = act ? (int)cur.y : 0;
      int ev = act ? (int)cur.x : 0;
      // gather: group grp handles edges jj = 4t+grp; unroll x2 for ILP
      const int steps = (nc + 3) >> 2;
      int t = 0;
      for (; t + 2 <= steps; t += 2) {
        int jj0 = (t << 2) + grp, jj1 = jj0 + 4;
        float w0 = __shfl(w, jj0), w1 = __shfl(w, jj1);
        int s0v = __shfl(sv, jj0), s1v = __shfl(sv, jj1);
        int e0v = __shfl(ev, jj0), e1v = __shfl(ev, jj1);
        const float4 z0 = *(const float4*)(z + (size_t)s0v * 64 + gl * 4);
        const float4 z1 = *(const float4*)(z + (size_t)s1v * 64 + gl * 4);
        float a0 = ea[(size_t)e0v * 16 + gl];
        float a1 = ea[(size_t)e1v * 16 + gl];
        msg.x = fmaf(w0, z0.x, fmaf(w1, z1.x, msg.x));
        msg.y = fmaf(w0, z0.y, fmaf(w1, z1.y, msg.y));
        msg.z = fmaf(w0, z0.z, fmaf(w1, z1.z, msg.z));
        msg.w = fmaf(w0, z0.w, fmaf(w1, z1.w, msg.w));
        ag = fmaf(w0, a0, fmaf(w1, a1, ag));
      }
      if (t < steps) {
        int jj0 = (t << 2) + grp;
        float w0 = __shfl(w, jj0);
        int s0v = __shfl(sv, jj0);
        int e0v = __shfl(ev, jj0);
        const float4 z0 = *(const float4*)(z + (size_t)s0v * 64 + gl * 4);
        float a0 = ea[(size_t)e0v * 16 + gl];
        msg.x = fmaf(w0, z0.x, msg.x);
        msg.y = fmaf(w0, z0.y, msg.y);
        msg.z = fmaf(w0, z0.z, msg.z);
        msg.w = fmaf(w0, z0.w, msg.w);
        ag = fmaf(w0, a0, ag);
      }
    }

    float dtot = wave_sum64(dsum);
    // combine the 4 groups' partials
    msg.x += __shfl_xor(msg.x, 16); msg.x += __shfl_xor(msg.x, 32);
    msg.y += __shfl_xor(msg.y, 16); msg.y += __shfl_xor(msg.y, 32);
    msg.z += __shfl_xor(msg.z, 16); msg.z += __shfl_xor(msg.z, 32);
    msg.w += __shfl_xor(msg.w, 16); msg.w += __shfl_xor(msg.w, 32);
    ag += __shfl_xor(ag, 16); ag += __shfl_xor(ag, 32);

    // evec = (Σ w·ea) @ We, per-lane float4 of columns 4gl..4gl+3
    const float4* We4 = (const float4*)We;
    float4 evec = make_float4(0.f, 0.f, 0.f, 0.f);
#pragma unroll
    for (int k = 0; k < 16; ++k) {
      float agk = __shfl(ag, k);
      float4 wef = We4[k * 16 + gl];
      evec.x = fmaf(agk, wef.x, evec.x);
      evec.y = fmaf(agk, wef.y, evec.y);
      evec.z = fmaf(agk, wef.z, evec.z);
      evec.w = fmaf(agk, wef.w, evec.w);
    }

    if (grp == 0) {
      float inv = 1.f / (dtot + 1e-8f);
      const float4 xr = *(const float4*)(x + (size_t)d * 64 + gl * 4);
      float4 r;
      r.x = fmaf(msg.x + evec.x, inv, xr.x);
      r.y = fmaf(msg.y + evec.y, inv, xr.y);
      r.z = fmaf(msg.z + evec.z, inv, xr.z);
      r.w = fmaf(msg.w + evec.w, inv, xr.w);
      *(float4*)(out + (size_t)d * 64 + gl * 4) = r;
    }

    d = dn; s0 = sn0; cnt = cn; rec = recn;
  }
}

extern "C" void kernel_launch(void* const* d_in, const int* in_sizes, int n_in,
                              void* d_out, int out_size, void* d_ws, size_t ws_size,
                              hipStream_t stream) {
  const float* x = (const float*)d_in[0];
  const int* ei = (const int*)d_in[1];
  const float* ea = (const float*)d_in[2];
  const float* Wn = (const float*)d_in[3];
  const float* We = (const float*)d_in[4];
  const float* att_src = (const float*)d_in[5];
  const float* att_dst = (const float*)d_in[6];
  const float* att_edge = (const float*)d_in[7];
  float* out = (float*)d_out;

  const int N = in_sizes[0] / 64;
  const int E = in_sizes[1] / 2;
  const int* src = ei;
  const int* dst = ei + E;

  // workspace carve (256B aligned)
  char* p = (char*)d_ws;
  auto carve = [&](size_t bytes) {
    void* q = (void*)p;
    p += (bytes + 255) & ~(size_t)255;
    return q;
  };
  float* z = (float*)carve((size_t)N * 64 * sizeof(float));
  float* zs = (float*)carve((size_t)N * sizeof(float));
  float* zd = (float*)carve((size_t)N * sizeof(float));
  int* count = (int*)carve((size_t)N * sizeof(int));
  int* startp = (int*)carve((size_t)N * sizeof(int));
  int* pos = (int*)carve((size_t)E * sizeof(int));
  float* weA = (float*)carve(64);
  int* total = (int*)carve(64);
  uint4* es = (uint4*)carve((size_t)E * sizeof(uint4));

  hipMemsetAsync(count, 0, (size_t)N * sizeof(int), stream);
  k_prep<<<1, 64, 0, stream>>>(We, att_edge, weA, total);
  k_countpos<<<(E + 255) / 256, 256, 0, stream>>>(dst, count, pos, E);
  k_node<<<2048, 256, 0, stream>>>(x, Wn, att_src, att_dst, z, zs, zd, N);
  k_offsets<<<(N + 255) / 256, 256, 0, stream>>>(count, startp, total, N);
  k_scatter<<<(E + 255) / 256, 256, 0, stream>>>(src, dst, pos, zs, zd, ea, weA,
                                                 startp, es, E);
  k_agg<<<4096, 256, 0, stream>>>(x, z, ea, We, startp, count, es, out, N);
}